// Round 15
// baseline (184.913 us; speedup 1.0000x reference)
//
#include <hip/hip_runtime.h>
#include <math.h>

#define CC 128      // channels (FIN=HID=OUT)

typedef unsigned short u16;
typedef short bf16x8 __attribute__((ext_vector_type(8)));
typedef float f32x4 __attribute__((ext_vector_type(4)));

typedef __attribute__((address_space(3))) void lds_t;
typedef const __attribute__((address_space(1))) void gbl_t;

__device__ __forceinline__ u16 f2bf(float f) {
    union { float f; unsigned u; } v; v.f = f;
    unsigned u = v.u;
    return (u16)((u + 0x7FFFu + ((u >> 16) & 1u)) >> 16);   // RNE
}
__device__ __forceinline__ float bf2f(unsigned hi16) {
    union { unsigned u; float f; } v; v.u = hi16 << 16; return v.f;
}
// HW packed f32->bf16 (RNE): 2 values in 1 instruction.
__device__ __forceinline__ unsigned cvt_pk(float lo, float hi) {
    unsigned r;
    asm("v_cvt_pk_bf16_f32 %0, %1, %2" : "=v"(r) : "v"(lo), "v"(hi));
    return r;
}

// Exact-GELU via branch-free A&S 7.1.26 erf (|err| < 1.5e-7).
__device__ __forceinline__ float gelu_f(float y) {
    float xa = fabsf(y) * 0.70710678118654752f;
    float t  = __builtin_amdgcn_rcpf(fmaf(0.3275911f, xa, 1.0f));
    float p  = fmaf(1.061405429f, t, -1.453152027f);
    p = fmaf(p, t, 1.421413741f);
    p = fmaf(p, t, -0.284496736f);
    p = fmaf(p, t, 0.254829592f);
    p *= t;
    float e  = __expf(-xa * xa);
    float er = fmaf(-p, e, 1.0f);
    float s  = copysignf(er, y);
    return 0.5f * y * (1.0f + s);
}

// ---------------- CSR build ----------------

__global__ __launch_bounds__(256) void k_hist(const int* __restrict__ row, int* __restrict__ cnt, int E) {
    int e = blockIdx.x * 256 + threadIdx.x;
    if (e < E) atomicAdd(&cnt[row[e]], 1);
}

__device__ __forceinline__ int wave_incl_scan(int v) {
    #pragma unroll
    for (int d = 1; d < 64; d <<= 1) {
        int t = __shfl_up(v, d);
        if ((threadIdx.x & 63) >= d) v += t;
    }
    return v;
}

__global__ __launch_bounds__(256) void k_scan_a(const int* __restrict__ cnt, int* __restrict__ bsum, int N) {
    int base = blockIdx.x * 1024 + threadIdx.x * 4;
    int s = 0;
    #pragma unroll
    for (int u = 0; u < 4; ++u) { int i = base + u; if (i < N) s += cnt[i]; }
    #pragma unroll
    for (int d = 32; d > 0; d >>= 1) s += __shfl_down(s, d);
    __shared__ int wsum[4];
    if ((threadIdx.x & 63) == 0) wsum[threadIdx.x >> 6] = s;
    __syncthreads();
    if (threadIdx.x == 0) bsum[blockIdx.x] = wsum[0] + wsum[1] + wsum[2] + wsum[3];
}

__global__ __launch_bounds__(64) void k_scan_b(const int* __restrict__ bsum, int* __restrict__ boff,
                                               int* __restrict__ off, int N, int nb) {
    int carry = 0;
    for (int base = 0; base < nb; base += 64) {
        int t = base + (int)threadIdx.x;
        int v = (t < nb) ? bsum[t] : 0;
        int incl = wave_incl_scan(v);
        if (t < nb) boff[t] = carry + incl - v;
        carry += __shfl(incl, 63);
    }
    if (threadIdx.x == 0) off[N] = carry;
}

__global__ __launch_bounds__(256) void k_scan_c(int* __restrict__ cnt, const int* __restrict__ boff,
                                                int* __restrict__ off, int N) {
    int t = threadIdx.x;
    int base = blockIdx.x * 1024 + t * 4;
    int v[4]; int s = 0;
    #pragma unroll
    for (int u = 0; u < 4; ++u) { int i = base + u; v[u] = (i < N) ? cnt[i] : 0; s += v[u]; }
    int incl = wave_incl_scan(s);
    __shared__ int wsum[4];
    int w = t >> 6, lane = t & 63;
    if (lane == 63) wsum[w] = incl;
    __syncthreads();
    int run = incl - s + boff[blockIdx.x];
    for (int ww = 0; ww < w; ++ww) run += wsum[ww];
    #pragma unroll
    for (int u = 0; u < 4; ++u) {
        int i = base + u;
        if (i < N) { off[i] = run; cnt[i] = 0; }
        run += v[u];
    }
}

__global__ __launch_bounds__(256) void k_fill(const int* __restrict__ row, const int* __restrict__ col,
                                              const float* __restrict__ nrm, const int* __restrict__ off,
                                              int* __restrict__ cur, int2* __restrict__ eg, int E) {
    int e = blockIdx.x * 256 + threadIdx.x;
    if (e < E) {
        int r = row[e];
        int p = off[r] + atomicAdd(&cur[r], 1);
        eg[p] = make_int2(col[e], __float_as_int(nrm[e]));
    }
}

// ---------------- prep: zero cur + W repacks + permuted bias b2p ----------------
// W1: standard k-order. W2: k-order permuted by pi(p) = (p&7)*16 + (p>>3).
// b2p[p] = b2[pi(p)] so the chunked aggregate can add bias in permuted-position space.
__global__ __launch_bounds__(256) void k_prep(int* __restrict__ cur, int N,
                                              const float* __restrict__ W1, u16* __restrict__ Wp1,
                                              const float* __restrict__ W2, u16* __restrict__ Wp2,
                                              const float* __restrict__ b2, float* __restrict__ b2p) {
    int i = blockIdx.x * 256 + threadIdx.x;
    if (i < N) { cur[i] = 0; return; }
    int iw = i - N;
    if (iw < 2 * CC * CC) {
        int is2 = (iw >= CC * CC);
        int ii = is2 ? iw - CC * CC : iw;
        int j = ii & 7, l = (ii >> 3) & 63, s = (ii >> 9) & 3, t = ii >> 11;
        int r = 16 * t + (l & 15);
        int p = s * 32 + ((l >> 4) & 3) * 8 + j;             // fragment k-position 0..127
        if (is2) {
            int k = (p & 7) * 16 + (p >> 3);                 // pi(p)
            Wp2[ii] = f2bf(W2[r * CC + k]);
        } else {
            Wp1[ii] = f2bf(W1[r * CC + p]);
        }
        return;
    }
    int ip = iw - 2 * CC * CC;
    if (ip < CC) b2p[ip] = b2[(ip & 7) * 16 + (ip >> 3)];
}

// ---------------- K1: persistent fused GEMM1+BN1+GELU1+GEMM2, barrier-free loop ----------
// Z stored CHUNK-MAJOR: Zc[chunk][node][32 values], chunk = batch*4 + pos/32 (permuted pos).
__global__ __launch_bounds__(256, 2) void k_fused_l1(
    const float* __restrict__ X, const u16* __restrict__ Wp1, const u16* __restrict__ Wp2,
    const float* __restrict__ bias, const float* __restrict__ gamma, const float* __restrict__ beta,
    u16* __restrict__ Zc, int N)
{
    __shared__ __align__(16) u16 WS1[CC * CC];        // 32KB, W1 resident
    __shared__ __align__(16) u16 WS2[CC * CC];        // 32KB, W2 resident
    __shared__ __align__(16) unsigned TT[4][16][64];  // 16KB, XOR-swizzled transpose

    const int tid = threadIdx.x;
    const int w = tid >> 6;
    const int l = tid & 63;
    const int g = l >> 4;
    const int c = l & 15;
    const int ntiles = (N + 31) / 32;
    const int NB = gridDim.x;

    #pragma unroll
    for (int it = 0; it < 8; ++it) {
        const u16* g1s = Wp1 + it * 2048 + w * 512 + l * 8;
        const u16* g2s = Wp2 + it * 2048 + w * 512 + l * 8;
        __builtin_amdgcn_global_load_lds((gbl_t*)g1s, (lds_t*)&WS1[it * 2048 + w * 512], 16, 0, 0);
        __builtin_amdgcn_global_load_lds((gbl_t*)g2s, (lds_t*)&WS2[it * 2048 + w * 512], 16, 0, 0);
    }

    float bb[8];
    #pragma unroll
    for (int t = 0; t < 8; ++t) bb[t] = bias[t * 16 + c];

    float4 xlo[4], xhi[4];
    float gamv[4], betv[4];
    auto prefetch = [&](int tt) {
        int n8 = tt * 32 + w * 8;
        int nb_ = (n8 < N) ? n8 : 0;
        const float* xb = X + ((size_t)(c >> 3) * N + nb_ + (c & 7)) * CC + g * 8;
        #pragma unroll
        for (int s = 0; s < 4; ++s) {
            xlo[s] = *(const float4*)(xb + s * 32);
            xhi[s] = *(const float4*)(xb + s * 32 + 4);
        }
        #pragma unroll
        for (int r = 0; r < 4; ++r) {
            int p = (4 * g + r) & 7;
            gamv[r] = gamma[nb_ + p];
            betv[r] = beta[nb_ + p];
        }
    };
    prefetch(blockIdx.x);

    __syncthreads();   // W1+W2 staged; the ONLY barrier

    for (int t = blockIdx.x; t < ntiles; t += NB) {
        const int n8 = t * 32 + w * 8;
        const bool valid = n8 < N;

        bf16x8 af[4];
        #pragma unroll
        for (int s = 0; s < 4; ++s) {
            unsigned aw[4];
            aw[0] = cvt_pk(xlo[s].x, xlo[s].y); aw[1] = cvt_pk(xlo[s].z, xlo[s].w);
            aw[2] = cvt_pk(xhi[s].x, xhi[s].y); aw[3] = cvt_pk(xhi[s].z, xhi[s].w);
            af[s] = *(bf16x8*)aw;
        }
        float gam[4], bet[4];
        #pragma unroll
        for (int r = 0; r < 4; ++r) { gam[r] = gamv[r]; bet[r] = betv[r]; }

        if (t + NB < ntiles) prefetch(t + NB);

        f32x4 acc[8];
        #pragma unroll
        for (int q = 0; q < 8; ++q) acc[q] = (f32x4){0.f, 0.f, 0.f, 0.f};
        #pragma unroll
        for (int s = 0; s < 4; ++s) {
            bf16x8 bf[8];
            #pragma unroll
            for (int q = 0; q < 8; ++q)
                bf[q] = *(const bf16x8*)&WS1[((q * 4 + s) * 64 + l) * 8];
            #pragma unroll
            for (int q = 0; q < 8; ++q)
                acc[q] = __builtin_amdgcn_mfma_f32_16x16x32_bf16(af[s], bf[q], acc[q], 0, 0, 0);
        }

        float rs[4] = {0.f, 0.f, 0.f, 0.f}, rq[4] = {0.f, 0.f, 0.f, 0.f};
        #pragma unroll
        for (int q = 0; q < 8; ++q)
            #pragma unroll
            for (int r = 0; r < 4; ++r) {
                float h = acc[q][r] + bb[q];
                acc[q][r] = h;
                rs[r] += h;
                rq[r] += h * h;
            }
        #pragma unroll
        for (int d = 1; d < 16; d <<= 1) {
            #pragma unroll
            for (int r = 0; r < 4; ++r) {
                rs[r] += __shfl_xor(rs[r], d);
                rq[r] += __shfl_xor(rq[r], d);
            }
        }
        #pragma unroll
        for (int r = 0; r < 4; ++r) {
            rs[r] += __shfl_xor(rs[r], 32);
            rq[r] += __shfl_xor(rq[r], 32);
        }

        #pragma unroll
        for (int r = 0; r < 4; ++r) {
            float mean = rs[r] * (1.f / 256.f);
            float var  = rq[r] * (1.f / 256.f) - mean * mean;
            float sc = gam[r] * rsqrtf(fmaxf(var, 0.f) + 1e-5f);
            float sh = bet[r] - mean * sc;
            #pragma unroll
            for (int q = 0; q < 8; ++q)
                acc[q][r] = gelu_f(acc[q][r] * sc + sh);
        }

        #pragma unroll
        for (int r = 0; r < 4; ++r) {
            int row = 4 * g + r;
            unsigned tw[4];
            #pragma unroll
            for (int tt = 0; tt < 4; ++tt)
                tw[tt] = cvt_pk(acc[2 * tt][r], acc[2 * tt + 1][r]);
            int colw = (c * 4) ^ ((row & 7) << 2);
            *(uint4*)&TT[w][row][colw] = *(uint4*)tw;
        }
        bf16x8 af2[4];
        #pragma unroll
        for (int s = 0; s < 4; ++s) {
            int colr = (s * 16 + g * 4) ^ ((c & 7) << 2);
            af2[s] = *(const bf16x8*)&TT[w][c][colr];
        }

        f32x4 acc2[8];
        #pragma unroll
        for (int q = 0; q < 8; ++q) acc2[q] = (f32x4){0.f, 0.f, 0.f, 0.f};
        #pragma unroll
        for (int s = 0; s < 4; ++s) {
            bf16x8 bf[8];
            #pragma unroll
            for (int q = 0; q < 8; ++q)
                bf[q] = *(const bf16x8*)&WS2[((q * 4 + s) * 64 + l) * 8];
            #pragma unroll
            for (int q = 0; q < 8; ++q)
                acc2[q] = __builtin_amdgcn_mfma_f32_16x16x32_bf16(af2[s], bf[q], acc2[q], 0, 0, 0);
        }

        // store Zc chunk-major: lane (g,c), row rr -> chunk = db*4 + (c>>2), offset (c&3)*8+t
        if (valid) {
            #pragma unroll
            for (int r = 0; r < 4; ++r) {
                int rr = 4 * g + r;
                int db = rr >> 3, dn = n8 + (rr & 7);
                unsigned zw[4];
                #pragma unroll
                for (int tt = 0; tt < 4; ++tt)
                    zw[tt] = cvt_pk(acc2[2 * tt][r], acc2[2 * tt + 1][r]);
                size_t chunk = (size_t)(db * 4 + (c >> 2));
                *(uint4*)(Zc + (chunk * N + dn) * 32 + (c & 3) * 8) = *(uint4*)zw;
            }
        }
    }
}

// ---------------- K2a: chunked SpMM aggregate + bias + per-chunk BN2 partial stats ------
// Block b -> chunk cid = b%8 (XCD-resident 3.2MB slice), node slice b/8 (16 nodes/block).
// Wave = 4 nodes; 16-lane group per node: es = edge slot (4 in flight), q = value quarter.
__global__ __launch_bounds__(256) void k_agg_chunk(
    const u16* __restrict__ Zc, const int* __restrict__ off, const int2* __restrict__ eg,
    const float* __restrict__ b2p, u16* __restrict__ H, float2* __restrict__ stats, int N)
{
    const int cid = blockIdx.x & 7;
    const int slice = blockIdx.x >> 3;
    const int wv = threadIdx.x >> 6;
    const int l = threadIdx.x & 63;
    const int ng = l >> 4;        // node within wave (4/wave)
    const int w16 = l & 15;
    const int es = w16 >> 2;      // edge slot 0..3
    const int q = w16 & 3;        // value quarter 0..3
    const int n = slice * 16 + wv * 4 + ng;
    const bool nv = n < N;
    const int nn = nv ? n : 0;
    const u16* Zb = Zc + ((size_t)cid * N) * 32 + q * 8;

    int s = off[nn];
    int e = nv ? off[nn + 1] : 0;
    float a[8] = {0.f, 0.f, 0.f, 0.f, 0.f, 0.f, 0.f, 0.f};
    for (int j = s; j < e; j += 4) {
        int idx = j + es;
        int2 ed = eg[idx];                       // +8 pad covers tail overread
        bool ok = idx < e;
        int   src = ok ? ed.x : 0;
        float wt  = ok ? __int_as_float(ed.y) : 0.f;
        bf16x8 v = *(const bf16x8*)(Zb + (size_t)src * 32);
        #pragma unroll
        for (int i = 0; i < 8; ++i)
            a[i] = fmaf(wt, bf2f((u16)v[i]), a[i]);
    }
    // reduce over edge slots (es occupies lane bits 2-3)
    #pragma unroll
    for (int i = 0; i < 8; ++i) {
        a[i] += __shfl_xor(a[i], 4);
        a[i] += __shfl_xor(a[i], 8);
    }
    // + bias (permuted positions p = (cid&3)*32 + q*8 + i), partial stats
    float ss = 0.f, qq = 0.f;
    #pragma unroll
    for (int i = 0; i < 8; ++i) {
        float h = a[i] + b2p[(cid & 3) * 32 + q * 8 + i];
        a[i] = h;
        ss += h;
        qq += h * h;
    }
    ss += __shfl_xor(ss, 1); ss += __shfl_xor(ss, 2);
    qq += __shfl_xor(qq, 1); qq += __shfl_xor(qq, 2);

    if (nv && es == 0) {
        unsigned hw[4];
        #pragma unroll
        for (int tt = 0; tt < 4; ++tt)
            hw[tt] = cvt_pk(a[2 * tt], a[2 * tt + 1]);
        *(uint4*)(H + ((size_t)cid * N + nn) * 32 + q * 8) = *(uint4*)hw;
        if (q == 0) stats[(size_t)cid * N + nn] = make_float2(ss, qq);
    }
}

// ---------------- K2b: BN2 + GELU2 + un-permute -> A2s (std-channel chunk-major) ---------
// 2 nodes/wave (32 lanes each). Stats: 8 partials reduced via shfl; values: lane reads 16B
// of H (permuted), BN+GELU, scatter to LDS in standard channel order, read back 16B, store.
__global__ __launch_bounds__(256) void k_bn2(
    const u16* __restrict__ H, const float2* __restrict__ stats,
    const float* __restrict__ g2, const float* __restrict__ be2,
    u16* __restrict__ A2s, int N)
{
    __shared__ u16 TR[4][2][256];
    const int wv = threadIdx.x >> 6;
    const int l = threadIdx.x & 63;
    const int half = l >> 5;
    const int hl = l & 31;
    const int n = blockIdx.x * 8 + wv * 2 + half;
    const bool nv = n < N;
    const int nn = nv ? n : 0;

    float ss = 0.f, qq = 0.f;
    if (hl < 8) {
        float2 st = stats[(size_t)hl * N + nn];
        ss = st.x; qq = st.y;
    }
    ss += __shfl_xor(ss, 1); ss += __shfl_xor(ss, 2); ss += __shfl_xor(ss, 4);
    qq += __shfl_xor(qq, 1); qq += __shfl_xor(qq, 2); qq += __shfl_xor(qq, 4);
    ss = __shfl(ss, half * 32);
    qq = __shfl(qq, half * 32);
    float mean = ss * (1.f / 256.f);
    float var  = qq * (1.f / 256.f) - mean * mean;
    float sc = g2[nn] * rsqrtf(fmaxf(var, 0.f) + 1e-5f);
    float sh = be2[nn] - mean * sc;

    // read 16B of H: chunk = hl>>2, offset (hl&3)*8; value pos p = (chunk&3)*32+(hl&3)*8+i
    const int chunk = hl >> 2;
    const int db = chunk >> 2;
    bf16x8 hv = *(const bf16x8*)(H + ((size_t)chunk * N + nn) * 32 + (hl & 3) * 8);
    // channel = i*16 + (hl&15) ; scatter to LDS std order
    #pragma unroll
    for (int i = 0; i < 8; ++i) {
        float y = bf2f((u16)hv[i]) * sc + sh;
        TR[wv][half][db * CC + i * 16 + (hl & 15)] = f2bf(gelu_f(y));
    }
    // read back standard-contiguous, store chunk-major: chunk' = hl>>2, off (hl&3)*8
    bf16x8 ov = *(const bf16x8*)&TR[wv][half][hl * 8];   // same-wave, lgkmcnt-ordered
    if (nv)
        *(bf16x8*)(A2s + ((size_t)(hl >> 2) * N + nn) * 32 + (hl & 3) * 8) = ov;
}

// ---------------- K3: chunked SpMM aggregate(A2s) -> standard f32 output -----------------
__global__ __launch_bounds__(256) void k_agg_out_chunk(
    const u16* __restrict__ A2s, const int* __restrict__ off, const int2* __restrict__ eg,
    float* __restrict__ Out, int N)
{
    const int cid = blockIdx.x & 7;
    const int slice = blockIdx.x >> 3;
    const int wv = threadIdx.x >> 6;
    const int l = threadIdx.x & 63;
    const int ng = l >> 4;
    const int w16 = l & 15;
    const int es = w16 >> 2;
    const int q = w16 & 3;
    const int n = slice * 16 + wv * 4 + ng;
    const bool nv = n < N;
    const int nn = nv ? n : 0;
    const u16* Ab = A2s + ((size_t)cid * N) * 32 + q * 8;

    int s = off[nn];
    int e = nv ? off[nn + 1] : 0;
    float a[8] = {0.f, 0.f, 0.f, 0.f, 0.f, 0.f, 0.f, 0.f};
    for (int j = s; j < e; j += 4) {
        int idx = j + es;
        int2 ed = eg[idx];
        bool ok = idx < e;
        int   src = ok ? ed.x : 0;
        float wt  = ok ? __int_as_float(ed.y) : 0.f;
        bf16x8 v = *(const bf16x8*)(Ab + (size_t)src * 32);
        #pragma unroll
        for (int i = 0; i < 8; ++i)
            a[i] = fmaf(wt, bf2f((u16)v[i]), a[i]);
    }
    #pragma unroll
    for (int i = 0; i < 8; ++i) {
        a[i] += __shfl_xor(a[i], 4);
        a[i] += __shfl_xor(a[i], 8);
    }
    if (nv && es == 0) {
        // std value v = cid*32 + q*8 + i -> batch = cid>>2, channel = (cid&3)*32 + q*8 + i
        float* d = Out + ((size_t)(cid >> 2) * N + nn) * CC + (cid & 3) * 32 + q * 8;
        *(float4*)&d[0] = make_float4(a[0], a[1], a[2], a[3]);
        *(float4*)&d[4] = make_float4(a[4], a[5], a[6], a[7]);
    }
}

// ---------------- launch ----------------

extern "C" void kernel_launch(void* const* d_in, const int* in_sizes, int n_in,
                              void* d_out, int out_size, void* d_ws, size_t ws_size,
                              hipStream_t stream)
{
    const float* x   = (const float*)d_in[0];
    const int*   ei  = (const int*)d_in[1];
    const float* nrm = (const float*)d_in[2];
    const float* W1  = (const float*)d_in[3];
    const float* b1  = (const float*)d_in[4];
    const float* g1  = (const float*)d_in[5];
    const float* be1 = (const float*)d_in[6];
    const float* W2  = (const float*)d_in[7];
    const float* b2  = (const float*)d_in[8];
    const float* g2  = (const float*)d_in[9];
    const float* be2 = (const float*)d_in[10];

    const int N = in_sizes[5];   // g1 has N elements
    const int E = in_sizes[2];   // norm has E elements
    const int* row = ei;         // edge_index[0] = scatter dst
    const int* col = ei + E;     // edge_index[1] = gather src
    const int nb = (N + 1023) / 1024;

    auto al = [](size_t v) { return (v + 255) & ~(size_t)255; };
    char* p = (char*)d_ws;
    int* off     = (int*)p;    p += al((size_t)(N + 1) * 4);
    int* cur     = (int*)p;    p += al((size_t)N * 4);
    int2* eg     = (int2*)p;   p += al((size_t)(E + 8) * 8);   // +8 pad: tail-slot overreads
    int* bsum    = (int*)p;    p += al((size_t)nb * 4);
    int* boff    = (int*)p;    p += al((size_t)nb * 4);
    u16* Wp1     = (u16*)p;    p += al((size_t)CC * CC * 2);
    u16* Wp2     = (u16*)p;    p += al((size_t)CC * CC * 2);
    float* b2p   = (float*)p;  p += al((size_t)CC * 4);
    u16* Zc      = (u16*)p;    p += al((size_t)2 * N * CC * 2);
    u16* Hbuf    = (u16*)p;    p += al((size_t)2 * N * CC * 2);
    u16* A2s     = (u16*)p;    p += al((size_t)2 * N * CC * 2);
    float2* stat = (float2*)p; p += al((size_t)8 * N * 8);

    // prep (zero cur + W repacks + b2p) then CSR by destination
    const int prep_n = N + 2 * CC * CC + CC;
    k_prep<<<(prep_n + 255) / 256, 256, 0, stream>>>(cur, N, W1, Wp1, W2, Wp2, b2, b2p);
    k_hist<<<(E + 255) / 256, 256, 0, stream>>>(row, cur, E);
    k_scan_a<<<nb, 256, 0, stream>>>(cur, bsum, N);
    k_scan_b<<<1, 64, 0, stream>>>(bsum, boff, off, N, nb);
    k_scan_c<<<nb, 256, 0, stream>>>(cur, boff, off, N);   // also zeroes cur
    k_fill<<<(E + 255) / 256, 256, 0, stream>>>(row, col, nrm, off, cur, eg, E);

    // K1: persistent fused GEMM1+BN1+GELU1+GEMM2 -> Zc (chunk-major)
    k_fused_l1<<<512, 256, 0, stream>>>(x, Wp1, Wp2, b1, g1, be1, Zc, N);

    const int nslice = (N + 15) / 16;
    // K2a: chunked aggregate (XCD-resident slices) + bias + partial stats -> H, stats
    k_agg_chunk<<<nslice * 8, 256, 0, stream>>>(Zc, off, eg, b2p, Hbuf, stat, N);
    // K2b: BN2 + GELU2 + un-permute -> A2s (std-channel chunk-major)
    k_bn2<<<(N + 7) / 8, 256, 0, stream>>>(Hbuf, stat, g2, be2, A2s, N);
    // K3: chunked aggregate -> standard f32 out
    k_agg_out_chunk<<<nslice * 8, 256, 0, stream>>>(A2s, off, eg, (float*)d_out, N);
}

// Round 16
// 165.325 us; speedup vs baseline: 1.1185x; 1.1185x over previous
//
#include <hip/hip_runtime.h>
#include <math.h>

#define CC 128      // channels (FIN=HID=OUT)

typedef unsigned short u16;
typedef short bf16x8 __attribute__((ext_vector_type(8)));
typedef float f32x4 __attribute__((ext_vector_type(4)));

typedef __attribute__((address_space(3))) void lds_t;
typedef const __attribute__((address_space(1))) void gbl_t;

__device__ __forceinline__ u16 f2bf(float f) {
    union { float f; unsigned u; } v; v.f = f;
    unsigned u = v.u;
    return (u16)((u + 0x7FFFu + ((u >> 16) & 1u)) >> 16);   // RNE
}
__device__ __forceinline__ float bf2f(unsigned hi16) {
    union { unsigned u; float f; } v; v.u = hi16 << 16; return v.f;
}
// HW packed f32->bf16 (RNE): 2 values in 1 instruction.
__device__ __forceinline__ unsigned cvt_pk(float lo, float hi) {
    unsigned r;
    asm("v_cvt_pk_bf16_f32 %0, %1, %2" : "=v"(r) : "v"(lo), "v"(hi));
    return r;
}

// Exact-GELU via branch-free A&S 7.1.26 erf (|err| < 1.5e-7).
__device__ __forceinline__ float gelu_f(float y) {
    float xa = fabsf(y) * 0.70710678118654752f;
    float t  = __builtin_amdgcn_rcpf(fmaf(0.3275911f, xa, 1.0f));
    float p  = fmaf(1.061405429f, t, -1.453152027f);
    p = fmaf(p, t, 1.421413741f);
    p = fmaf(p, t, -0.284496736f);
    p = fmaf(p, t, 0.254829592f);
    p *= t;
    float e  = __expf(-xa * xa);
    float er = fmaf(-p, e, 1.0f);
    float s  = copysignf(er, y);
    return 0.5f * y * (1.0f + s);
}

// ---------------- CSR build ----------------

__global__ __launch_bounds__(256) void k_hist(const int* __restrict__ row, int* __restrict__ cnt, int E) {
    int e = blockIdx.x * 256 + threadIdx.x;
    if (e < E) atomicAdd(&cnt[row[e]], 1);
}

__device__ __forceinline__ int wave_incl_scan(int v) {
    #pragma unroll
    for (int d = 1; d < 64; d <<= 1) {
        int t = __shfl_up(v, d);
        if ((threadIdx.x & 63) >= d) v += t;
    }
    return v;
}

__global__ __launch_bounds__(256) void k_scan_a(const int* __restrict__ cnt, int* __restrict__ bsum, int N) {
    int base = blockIdx.x * 1024 + threadIdx.x * 4;
    int s = 0;
    #pragma unroll
    for (int u = 0; u < 4; ++u) { int i = base + u; if (i < N) s += cnt[i]; }
    #pragma unroll
    for (int d = 32; d > 0; d >>= 1) s += __shfl_down(s, d);
    __shared__ int wsum[4];
    if ((threadIdx.x & 63) == 0) wsum[threadIdx.x >> 6] = s;
    __syncthreads();
    if (threadIdx.x == 0) bsum[blockIdx.x] = wsum[0] + wsum[1] + wsum[2] + wsum[3];
}

__global__ __launch_bounds__(64) void k_scan_b(const int* __restrict__ bsum, int* __restrict__ boff,
                                               int* __restrict__ off, int N, int nb) {
    int carry = 0;
    for (int base = 0; base < nb; base += 64) {
        int t = base + (int)threadIdx.x;
        int v = (t < nb) ? bsum[t] : 0;
        int incl = wave_incl_scan(v);
        if (t < nb) boff[t] = carry + incl - v;
        carry += __shfl(incl, 63);
    }
    if (threadIdx.x == 0) off[N] = carry;
}

__global__ __launch_bounds__(256) void k_scan_c(int* __restrict__ cnt, const int* __restrict__ boff,
                                                int* __restrict__ off, int N) {
    int t = threadIdx.x;
    int base = blockIdx.x * 1024 + t * 4;
    int v[4]; int s = 0;
    #pragma unroll
    for (int u = 0; u < 4; ++u) { int i = base + u; v[u] = (i < N) ? cnt[i] : 0; s += v[u]; }
    int incl = wave_incl_scan(s);
    __shared__ int wsum[4];
    int w = t >> 6, lane = t & 63;
    if (lane == 63) wsum[w] = incl;
    __syncthreads();
    int run = incl - s + boff[blockIdx.x];
    for (int ww = 0; ww < w; ++ww) run += wsum[ww];
    #pragma unroll
    for (int u = 0; u < 4; ++u) {
        int i = base + u;
        if (i < N) { off[i] = run; cnt[i] = 0; }
        run += v[u];
    }
}

__global__ __launch_bounds__(256) void k_fill(const int* __restrict__ row, const int* __restrict__ col,
                                              const float* __restrict__ nrm, const int* __restrict__ off,
                                              int* __restrict__ cur, int2* __restrict__ eg, int E) {
    int e = blockIdx.x * 256 + threadIdx.x;
    if (e < E) {
        int r = row[e];
        int p = off[r] + atomicAdd(&cur[r], 1);
        eg[p] = make_int2(col[e], __float_as_int(nrm[e]));
    }
}

// ---------------- prep: zero cur  +  W repack into MFMA B-fragment order ----------------
__global__ __launch_bounds__(256) void k_prep(int* __restrict__ cur, int N,
                                              const float* __restrict__ W1, u16* __restrict__ Wp1,
                                              const float* __restrict__ W2, u16* __restrict__ Wp2) {
    int i = blockIdx.x * 256 + threadIdx.x;
    if (i < N) { cur[i] = 0; return; }
    int iw = i - N;
    if (iw < 2 * CC * CC) {
        int is2 = (iw >= CC * CC);
        int ii = is2 ? iw - CC * CC : iw;
        int j = ii & 7, l = (ii >> 3) & 63, s = (ii >> 9) & 3, t = ii >> 11;
        int r = 16 * t + (l & 15);
        int p = s * 32 + ((l >> 4) & 3) * 8 + j;             // fragment k-position 0..127
        if (is2) {
            int k = (p & 7) * 16 + (p >> 3);                 // pi(p)
            Wp2[ii] = f2bf(W2[r * CC + k]);
        } else {
            Wp1[ii] = f2bf(W1[r * CC + p]);
        }
    }
}

// ---------------- X -> bf16, packed into A-fragment-contiguous order ----------------
// Xp[((tile*4+w)*64+l)*32 + s*8 + j] = bf16( X[b][n][ch] ), c=l&15, g=l>>4, b=c>>3,
// n = tile*32 + w*8 + (c&7), ch = g*8 + s*32 + j.  A wave's per-tile X read becomes
// 4 perfectly-coalesced 1KB loads (lane-contiguous 16B each), replacing the strided
// 32B-granule pattern that capped K1 at ~1.3 TB/s.  Streaming pass at max occupancy.
__global__ __launch_bounds__(256) void k_xpack(const float* __restrict__ X, u16* __restrict__ Xp,
                                               int N, int ntotal) {
    int idx = blockIdx.x * 256 + threadIdx.x;   // one (tile,w,l,s) cell = 8 values
    if (idx >= ntotal) return;
    int s = idx & 3;
    int l = (idx >> 2) & 63;
    int tw = idx >> 8;                          // tile*4 + w
    int c = l & 15, g = l >> 4;
    int b = c >> 3;
    int n = (tw >> 2) * 32 + (tw & 3) * 8 + (c & 7);
    int ch = g * 8 + s * 32;
    bf16x8 v = {0, 0, 0, 0, 0, 0, 0, 0};
    if (n < N) {
        const float* src = X + ((size_t)b * N + n) * CC + ch;
        float4 lo = *(const float4*)src;
        float4 hi = *(const float4*)(src + 4);
        unsigned aw[4];
        aw[0] = cvt_pk(lo.x, lo.y); aw[1] = cvt_pk(lo.z, lo.w);
        aw[2] = cvt_pk(hi.x, hi.y); aw[3] = cvt_pk(hi.z, hi.w);
        v = *(bf16x8*)aw;
    }
    *(bf16x8*)(Xp + (size_t)idx * 8) = v;
}

// ---------------- K1: persistent fused GEMM1+BN1+GELU1+GEMM2, barrier-free loop ----------
// Reads pre-packed Xp (fully coalesced); W1+W2 resident in LDS; TT XOR-swizzled; Z stored
// node-major interleaved Z[node][batch][128] in permuted channel order.
__global__ __launch_bounds__(256, 2) void k_fused_l1(
    const u16* __restrict__ Xp, const u16* __restrict__ Wp1, const u16* __restrict__ Wp2,
    const float* __restrict__ bias, const float* __restrict__ gamma, const float* __restrict__ beta,
    u16* __restrict__ Z, int N)
{
    __shared__ __align__(16) u16 WS1[CC * CC];        // 32KB, W1 resident
    __shared__ __align__(16) u16 WS2[CC * CC];        // 32KB, W2 resident
    __shared__ __align__(16) unsigned TT[4][16][64];  // 16KB, XOR-swizzled transpose

    const int tid = threadIdx.x;
    const int w = tid >> 6;
    const int l = tid & 63;
    const int g = l >> 4;
    const int c = l & 15;
    const int ntiles = (N + 31) / 32;
    const int NB = gridDim.x;

    #pragma unroll
    for (int it = 0; it < 8; ++it) {
        const u16* g1s = Wp1 + it * 2048 + w * 512 + l * 8;
        const u16* g2s = Wp2 + it * 2048 + w * 512 + l * 8;
        __builtin_amdgcn_global_load_lds((gbl_t*)g1s, (lds_t*)&WS1[it * 2048 + w * 512], 16, 0, 0);
        __builtin_amdgcn_global_load_lds((gbl_t*)g2s, (lds_t*)&WS2[it * 2048 + w * 512], 16, 0, 0);
    }

    float bb[8];
    #pragma unroll
    for (int t = 0; t < 8; ++t) bb[t] = bias[t * 16 + c];

    bf16x8 afp[4];
    float gamv[4], betv[4];
    auto prefetch = [&](int tt) {
        const u16* xb = Xp + (((size_t)tt * 4 + w) * 64 + l) * 32;
        #pragma unroll
        for (int s = 0; s < 4; ++s) afp[s] = *(const bf16x8*)(xb + s * 8);
        int n8 = tt * 32 + w * 8;
        int nb_ = (n8 < N) ? n8 : 0;
        #pragma unroll
        for (int r = 0; r < 4; ++r) {
            int p = (4 * g + r) & 7;
            gamv[r] = gamma[nb_ + p];
            betv[r] = beta[nb_ + p];
        }
    };
    prefetch(blockIdx.x);

    __syncthreads();   // W1+W2 staged; the ONLY barrier

    for (int t = blockIdx.x; t < ntiles; t += NB) {
        const int n8 = t * 32 + w * 8;
        const bool valid = n8 < N;

        bf16x8 af[4];
        #pragma unroll
        for (int s = 0; s < 4; ++s) af[s] = afp[s];
        float gam[4], bet[4];
        #pragma unroll
        for (int r = 0; r < 4; ++r) { gam[r] = gamv[r]; bet[r] = betv[r]; }

        if (t + NB < ntiles) prefetch(t + NB);

        f32x4 acc[8];
        #pragma unroll
        for (int q = 0; q < 8; ++q) acc[q] = (f32x4){0.f, 0.f, 0.f, 0.f};
        #pragma unroll
        for (int s = 0; s < 4; ++s) {
            bf16x8 bf[8];
            #pragma unroll
            for (int q = 0; q < 8; ++q)
                bf[q] = *(const bf16x8*)&WS1[((q * 4 + s) * 64 + l) * 8];
            #pragma unroll
            for (int q = 0; q < 8; ++q)
                acc[q] = __builtin_amdgcn_mfma_f32_16x16x32_bf16(af[s], bf[q], acc[q], 0, 0, 0);
        }

        float rs[4] = {0.f, 0.f, 0.f, 0.f}, rq[4] = {0.f, 0.f, 0.f, 0.f};
        #pragma unroll
        for (int q = 0; q < 8; ++q)
            #pragma unroll
            for (int r = 0; r < 4; ++r) {
                float h = acc[q][r] + bb[q];
                acc[q][r] = h;
                rs[r] += h;
                rq[r] += h * h;
            }
        #pragma unroll
        for (int d = 1; d < 16; d <<= 1) {
            #pragma unroll
            for (int r = 0; r < 4; ++r) {
                rs[r] += __shfl_xor(rs[r], d);
                rq[r] += __shfl_xor(rq[r], d);
            }
        }
        #pragma unroll
        for (int r = 0; r < 4; ++r) {
            rs[r] += __shfl_xor(rs[r], 32);
            rq[r] += __shfl_xor(rq[r], 32);
        }

        #pragma unroll
        for (int r = 0; r < 4; ++r) {
            float mean = rs[r] * (1.f / 256.f);
            float var  = rq[r] * (1.f / 256.f) - mean * mean;
            float sc = gam[r] * rsqrtf(fmaxf(var, 0.f) + 1e-5f);
            float sh = bet[r] - mean * sc;
            #pragma unroll
            for (int q = 0; q < 8; ++q)
                acc[q][r] = gelu_f(acc[q][r] * sc + sh);
        }

        #pragma unroll
        for (int r = 0; r < 4; ++r) {
            int row = 4 * g + r;
            unsigned tw_[4];
            #pragma unroll
            for (int tt = 0; tt < 4; ++tt)
                tw_[tt] = cvt_pk(acc[2 * tt][r], acc[2 * tt + 1][r]);
            int colw = (c * 4) ^ ((row & 7) << 2);
            *(uint4*)&TT[w][row][colw] = *(uint4*)tw_;
        }
        bf16x8 af2[4];
        #pragma unroll
        for (int s = 0; s < 4; ++s) {
            int colr = (s * 16 + g * 4) ^ ((c & 7) << 2);
            af2[s] = *(const bf16x8*)&TT[w][c][colr];
        }

        f32x4 acc2[8];
        #pragma unroll
        for (int q = 0; q < 8; ++q) acc2[q] = (f32x4){0.f, 0.f, 0.f, 0.f};
        #pragma unroll
        for (int s = 0; s < 4; ++s) {
            bf16x8 bf[8];
            #pragma unroll
            for (int q = 0; q < 8; ++q)
                bf[q] = *(const bf16x8*)&WS2[((q * 4 + s) * 64 + l) * 8];
            #pragma unroll
            for (int q = 0; q < 8; ++q)
                acc2[q] = __builtin_amdgcn_mfma_f32_16x16x32_bf16(af2[s], bf[q], acc2[q], 0, 0, 0);
        }

        if (valid) {
            #pragma unroll
            for (int r = 0; r < 4; ++r) {
                int rr = 4 * g + r;
                int db = rr >> 3, dn = n8 + (rr & 7);
                unsigned zw[4];
                #pragma unroll
                for (int tt = 0; tt < 4; ++tt)
                    zw[tt] = cvt_pk(acc2[2 * tt][r], acc2[2 * tt + 1][r]);
                *(uint4*)(Z + ((size_t)dn * 2 + db) * CC + c * 8) = *(uint4*)zw;
            }
        }
    }
}

// ---------------- K2: aggregate(Z) + b2 + BN2 + GELU2 -> a2 (standard order) ----------------
// TWO nodes per wave (one per 32-lane half); edge loop 4-deep unrolled per half.
__global__ __launch_bounds__(256) void k_agg_bn(
    const u16* __restrict__ Zin, const int* __restrict__ off, const int2* __restrict__ eg,
    const float* __restrict__ b2, const float* __restrict__ g2, const float* __restrict__ be2,
    u16* __restrict__ A2, int N)
{
    __shared__ u16 TW[4][2][256];
    const int wv = threadIdx.x >> 6;
    const int l = threadIdx.x & 63;
    const int half = l >> 5;
    const int h = l & 31;
    const int b = h >> 4;
    const int c = h & 15;
    const int n = blockIdx.x * 8 + wv * 2 + half;
    const bool nv = n < N;
    const int nn = nv ? n : 0;
    const u16* Ab = Zin + b * CC + c * 8;

    float bb[8];
    #pragma unroll
    for (int t = 0; t < 8; ++t) bb[t] = b2[t * 16 + c];

    int s = off[nn];
    int e = nv ? off[nn + 1] : 0;
    float a[8] = {0.f, 0.f, 0.f, 0.f, 0.f, 0.f, 0.f, 0.f};
    for (int j = s; j < e; j += 4) {
        int2 e0 = eg[j], e1 = eg[j + 1], e2 = eg[j + 2], e3 = eg[j + 3];
        int s0 = e0.x;                  float w0 = __int_as_float(e0.y);
        int s1 = (j + 1 < e) ? e1.x : 0; float w1 = (j + 1 < e) ? __int_as_float(e1.y) : 0.f;
        int s2 = (j + 2 < e) ? e2.x : 0; float w2 = (j + 2 < e) ? __int_as_float(e2.y) : 0.f;
        int s3 = (j + 3 < e) ? e3.x : 0; float w3 = (j + 3 < e) ? __int_as_float(e3.y) : 0.f;
        bf16x8 v0 = *(const bf16x8*)(Ab + (size_t)s0 * 256);
        bf16x8 v1 = *(const bf16x8*)(Ab + (size_t)s1 * 256);
        bf16x8 v2 = *(const bf16x8*)(Ab + (size_t)s2 * 256);
        bf16x8 v3 = *(const bf16x8*)(Ab + (size_t)s3 * 256);
        #pragma unroll
        for (int q = 0; q < 8; ++q) {
            a[q] = fmaf(w0, bf2f((u16)v0[q]), a[q]);
            a[q] = fmaf(w1, bf2f((u16)v1[q]), a[q]);
            a[q] = fmaf(w2, bf2f((u16)v2[q]), a[q]);
            a[q] = fmaf(w3, bf2f((u16)v3[q]), a[q]);
        }
    }

    float ss = 0.f, qq = 0.f;
    #pragma unroll
    for (int t = 0; t < 8; ++t) {
        float hh = a[t] + bb[t];
        a[t] = hh;
        ss += hh;
        qq += hh * hh;
    }
    #pragma unroll
    for (int d = 1; d < 32; d <<= 1) {   // stays within the 32-lane half
        ss += __shfl_xor(ss, d);
        qq += __shfl_xor(qq, d);
    }
    float mean = ss * (1.f / 256.f);
    float var  = qq * (1.f / 256.f) - mean * mean;
    float sc = g2[nn] * rsqrtf(fmaxf(var, 0.f) + 1e-5f);
    float sh = be2[nn] - mean * sc;

    #pragma unroll
    for (int t = 0; t < 8; ++t)
        TW[wv][half][b * CC + t * 16 + c] = f2bf(gelu_f(a[t] * sc + sh));
    if (nv) {
        bf16x8 v = *(const bf16x8*)&TW[wv][half][h * 8];
        *(bf16x8*)(A2 + (size_t)nn * 256 + h * 8) = v;
    }
}

// ---------------- K3: aggregate(a2) -> standard-layout f32 output ----------------
__global__ __launch_bounds__(256) void k_agg_out(
    const u16* __restrict__ A2, const int* __restrict__ off, const int2* __restrict__ eg,
    float* __restrict__ Out, int N)
{
    const int wv = threadIdx.x >> 6;
    const int l = threadIdx.x & 63;
    const int half = l >> 5;
    const int h = l & 31;
    const int b = h >> 4;
    const int c = h & 15;
    const int n = blockIdx.x * 8 + wv * 2 + half;
    const bool nv = n < N;
    const int nn = nv ? n : 0;
    const u16* Ab = A2 + h * 8;

    int s = off[nn];
    int e = nv ? off[nn + 1] : 0;
    float a[8] = {0.f, 0.f, 0.f, 0.f, 0.f, 0.f, 0.f, 0.f};
    for (int j = s; j < e; j += 4) {
        int2 e0 = eg[j], e1 = eg[j + 1], e2 = eg[j + 2], e3 = eg[j + 3];
        int s0 = e0.x;                  float w0 = __int_as_float(e0.y);
        int s1 = (j + 1 < e) ? e1.x : 0; float w1 = (j + 1 < e) ? __int_as_float(e1.y) : 0.f;
        int s2 = (j + 2 < e) ? e2.x : 0; float w2 = (j + 2 < e) ? __int_as_float(e2.y) : 0.f;
        int s3 = (j + 3 < e) ? e3.x : 0; float w3 = (j + 3 < e) ? __int_as_float(e3.y) : 0.f;
        bf16x8 v0 = *(const bf16x8*)(Ab + (size_t)s0 * 256);
        bf16x8 v1 = *(const bf16x8*)(Ab + (size_t)s1 * 256);
        bf16x8 v2 = *(const bf16x8*)(Ab + (size_t)s2 * 256);
        bf16x8 v3 = *(const bf16x8*)(Ab + (size_t)s3 * 256);
        #pragma unroll
        for (int q = 0; q < 8; ++q) {
            a[q] = fmaf(w0, bf2f((u16)v0[q]), a[q]);
            a[q] = fmaf(w1, bf2f((u16)v1[q]), a[q]);
            a[q] = fmaf(w2, bf2f((u16)v2[q]), a[q]);
            a[q] = fmaf(w3, bf2f((u16)v3[q]), a[q]);
        }
    }
    if (nv) {
        float* d = Out + ((size_t)b * N + nn) * CC + c * 8;
        *(float4*)&d[0] = make_float4(a[0], a[1], a[2], a[3]);
        *(float4*)&d[4] = make_float4(a[4], a[5], a[6], a[7]);
    }
}

// ---------------- launch ----------------

extern "C" void kernel_launch(void* const* d_in, const int* in_sizes, int n_in,
                              void* d_out, int out_size, void* d_ws, size_t ws_size,
                              hipStream_t stream)
{
    const float* x   = (const float*)d_in[0];
    const int*   ei  = (const int*)d_in[1];
    const float* nrm = (const float*)d_in[2];
    const float* W1  = (const float*)d_in[3];
    const float* b1  = (const float*)d_in[4];
    const float* g1  = (const float*)d_in[5];
    const float* be1 = (const float*)d_in[6];
    const float* W2  = (const float*)d_in[7];
    const float* b2  = (const float*)d_in[8];
    const float* g2  = (const float*)d_in[9];
    const float* be2 = (const float*)d_in[10];

    const int N = in_sizes[5];   // g1 has N elements
    const int E = in_sizes[2];   // norm has E elements
    const int* row = ei;         // edge_index[0] = scatter dst
    const int* col = ei + E;     // edge_index[1] = gather src
    const int nb = (N + 1023) / 1024;
    const int nt = (N + 31) / 32;

    auto al = [](size_t v) { return (v + 255) & ~(size_t)255; };
    char* p = (char*)d_ws;
    int* off    = (int*)p;   p += al((size_t)(N + 1) * 4);
    int* cur    = (int*)p;   p += al((size_t)N * 4);
    int2* eg    = (int2*)p;  p += al((size_t)(E + 8) * 8);   // +8 pad: tail-slot overreads
    int* bsum   = (int*)p;   p += al((size_t)nb * 4);
    int* boff   = (int*)p;   p += al((size_t)nb * 4);
    u16* Wp1    = (u16*)p;   p += al((size_t)CC * CC * 2);
    u16* Wp2    = (u16*)p;   p += al((size_t)CC * CC * 2);
    u16* Xp     = (u16*)p;   p += al((size_t)nt * 8192 * 2); // packed X (bf16 frag order)
    u16* Zbuf   = (u16*)p;   p += al((size_t)2 * N * CC * 2);
    u16* A2buf  = (u16*)p;   p += al((size_t)2 * N * CC * 2);

    // prep (zero cur + W repacks), X pack, then CSR by destination
    const int prep_n = N + 2 * CC * CC;
    k_prep<<<(prep_n + 255) / 256, 256, 0, stream>>>(cur, N, W1, Wp1, W2, Wp2);
    k_xpack<<<nt * 4, 256, 0, stream>>>(x, Xp, N, nt * 1024);
    k_hist<<<(E + 255) / 256, 256, 0, stream>>>(row, cur, E);
    k_scan_a<<<nb, 256, 0, stream>>>(cur, bsum, N);
    k_scan_b<<<1, 64, 0, stream>>>(bsum, boff, off, N, nb);
    k_scan_c<<<nb, 256, 0, stream>>>(cur, boff, off, N);   // also zeroes cur
    k_fill<<<(E + 255) / 256, 256, 0, stream>>>(row, col, nrm, off, cur, eg, E);

    const int ga = (N + 7) / 8;
    // K1: persistent fused GEMM1+BN1+GELU1+GEMM2 -> Z
    k_fused_l1<<<512, 256, 0, stream>>>(Xp, Wp1, Wp2, b1, g1, be1, Zbuf, N);
    // K2: aggregate + b2 + BN2 + GELU2 -> a2 (node-major, standard channel order)
    k_agg_bn<<<ga, 256, 0, stream>>>(Zbuf, off, eg, b2, g2, be2, A2buf, N);
    // K3: aggregate -> standard f32 out (coalesced)
    k_agg_out<<<ga, 256, 0, stream>>>(A2buf, off, eg, (float*)d_out, N);
}

// Round 17
// 147.953 us; speedup vs baseline: 1.2498x; 1.1174x over previous
//
#include <hip/hip_runtime.h>
#include <math.h>

#define CC 128      // channels (FIN=HID=OUT)

typedef unsigned short u16;
typedef short bf16x8 __attribute__((ext_vector_type(8)));
typedef float f32x4 __attribute__((ext_vector_type(4)));

typedef __attribute__((address_space(3))) void lds_t;
typedef const __attribute__((address_space(1))) void gbl_t;

__device__ __forceinline__ u16 f2bf(float f) {
    union { float f; unsigned u; } v; v.f = f;
    unsigned u = v.u;
    return (u16)((u + 0x7FFFu + ((u >> 16) & 1u)) >> 16);   // RNE
}
__device__ __forceinline__ float bf2f(unsigned hi16) {
    union { unsigned u; float f; } v; v.u = hi16 << 16; return v.f;
}
// HW packed f32->bf16 (RNE): 2 values in 1 instruction.
__device__ __forceinline__ unsigned cvt_pk(float lo, float hi) {
    unsigned r;
    asm("v_cvt_pk_bf16_f32 %0, %1, %2" : "=v"(r) : "v"(lo), "v"(hi));
    return r;
}

// Exact-GELU via branch-free A&S 7.1.26 erf (|err| < 1.5e-7).
__device__ __forceinline__ float gelu_f(float y) {
    float xa = fabsf(y) * 0.70710678118654752f;
    float t  = __builtin_amdgcn_rcpf(fmaf(0.3275911f, xa, 1.0f));
    float p  = fmaf(1.061405429f, t, -1.453152027f);
    p = fmaf(p, t, 1.421413741f);
    p = fmaf(p, t, -0.284496736f);
    p = fmaf(p, t, 0.254829592f);
    p *= t;
    float e  = __expf(-xa * xa);
    float er = fmaf(-p, e, 1.0f);
    float s  = copysignf(er, y);
    return 0.5f * y * (1.0f + s);
}

// ---------------- CSR build ----------------

__global__ __launch_bounds__(256) void k_hist(const int* __restrict__ row, int* __restrict__ cnt, int E) {
    int e = blockIdx.x * 256 + threadIdx.x;
    if (e < E) atomicAdd(&cnt[row[e]], 1);
}

__device__ __forceinline__ int wave_incl_scan(int v) {
    #pragma unroll
    for (int d = 1; d < 64; d <<= 1) {
        int t = __shfl_up(v, d);
        if ((threadIdx.x & 63) >= d) v += t;
    }
    return v;
}

__global__ __launch_bounds__(256) void k_scan_a(const int* __restrict__ cnt, int* __restrict__ bsum, int N) {
    int base = blockIdx.x * 1024 + threadIdx.x * 4;
    int s = 0;
    #pragma unroll
    for (int u = 0; u < 4; ++u) { int i = base + u; if (i < N) s += cnt[i]; }
    #pragma unroll
    for (int d = 32; d > 0; d >>= 1) s += __shfl_down(s, d);
    __shared__ int wsum[4];
    if ((threadIdx.x & 63) == 0) wsum[threadIdx.x >> 6] = s;
    __syncthreads();
    if (threadIdx.x == 0) bsum[blockIdx.x] = wsum[0] + wsum[1] + wsum[2] + wsum[3];
}

// local scan + self-computed block prefix (folds old scan_b in); also zeroes cnt for k_fill.
__global__ __launch_bounds__(256) void k_scan_c(int* __restrict__ cnt, const int* __restrict__ bsum,
                                                int* __restrict__ off, int N) {
    int t = threadIdx.x;

    // block prefix: sum of bsum[0..blockIdx.x) computed redundantly per block
    int part = 0;
    for (int j = t; j < (int)blockIdx.x; j += 256) part += bsum[j];
    #pragma unroll
    for (int d = 32; d > 0; d >>= 1) part += __shfl_down(part, d);
    __shared__ int psum[4];
    if ((t & 63) == 0) psum[t >> 6] = part;
    __syncthreads();
    const int boff = psum[0] + psum[1] + psum[2] + psum[3];

    int base = blockIdx.x * 1024 + t * 4;
    int v[4]; int s = 0;
    #pragma unroll
    for (int u = 0; u < 4; ++u) { int i = base + u; v[u] = (i < N) ? cnt[i] : 0; s += v[u]; }
    int incl = wave_incl_scan(s);
    __shared__ int wsum[4];
    int w = t >> 6, lane = t & 63;
    if (lane == 63) wsum[w] = incl;
    __syncthreads();
    int run = incl - s + boff;
    for (int ww = 0; ww < w; ++ww) run += wsum[ww];
    #pragma unroll
    for (int u = 0; u < 4; ++u) {
        int i = base + u;
        if (i < N) { off[i] = run; cnt[i] = 0; }
        run += v[u];
    }
    if (blockIdx.x == gridDim.x - 1 && t == 0)
        off[N] = boff + bsum[blockIdx.x];
}

__global__ __launch_bounds__(256) void k_fill(const int* __restrict__ row, const int* __restrict__ col,
                                              const float* __restrict__ nrm, const int* __restrict__ off,
                                              int* __restrict__ cur, int2* __restrict__ eg, int E) {
    int e = blockIdx.x * 256 + threadIdx.x;
    if (e < E) {
        int r = row[e];
        int p = off[r] + atomicAdd(&cur[r], 1);
        eg[p] = make_int2(col[e], __float_as_int(nrm[e]));
    }
}

// ---------------- prep: zero cur  +  W repack into MFMA B-fragment order ----------------
__global__ __launch_bounds__(256) void k_prep(int* __restrict__ cur, int N,
                                              const float* __restrict__ W1, u16* __restrict__ Wp1,
                                              const float* __restrict__ W2, u16* __restrict__ Wp2) {
    int i = blockIdx.x * 256 + threadIdx.x;
    if (i < N) { cur[i] = 0; return; }
    int iw = i - N;
    if (iw < 2 * CC * CC) {
        int is2 = (iw >= CC * CC);
        int ii = is2 ? iw - CC * CC : iw;
        int j = ii & 7, l = (ii >> 3) & 63, s = (ii >> 9) & 3, t = ii >> 11;
        int r = 16 * t + (l & 15);
        int p = s * 32 + ((l >> 4) & 3) * 8 + j;             // fragment k-position 0..127
        if (is2) {
            int k = (p & 7) * 16 + (p >> 3);                 // pi(p)
            Wp2[ii] = f2bf(W2[r * CC + k]);
        } else {
            Wp1[ii] = f2bf(W1[r * CC + p]);
        }
    }
}

// ---------------- K1: persistent fused GEMM1+BN1+GELU1+GEMM2, barrier-free loop ----------
// W1 AND W2 staged once per block (64KB); TT transpose = 16KB XOR-swizzled. LDS = 80KB ->
// 2 blocks/CU. Each block loops over tiles (32 nodes each) with ZERO in-loop barriers.
__global__ __launch_bounds__(256, 2) void k_fused_l1(
    const float* __restrict__ X, const u16* __restrict__ Wp1, const u16* __restrict__ Wp2,
    const float* __restrict__ bias, const float* __restrict__ gamma, const float* __restrict__ beta,
    u16* __restrict__ Z, int N)
{
    __shared__ __align__(16) u16 WS1[CC * CC];        // 32KB, W1 resident
    __shared__ __align__(16) u16 WS2[CC * CC];        // 32KB, W2 resident
    __shared__ __align__(16) unsigned TT[4][16][64];  // 16KB, XOR-swizzled transpose

    const int tid = threadIdx.x;
    const int w = tid >> 6;
    const int l = tid & 63;
    const int g = l >> 4;
    const int c = l & 15;
    const int ntiles = (N + 31) / 32;
    const int NB = gridDim.x;

    #pragma unroll
    for (int it = 0; it < 8; ++it) {
        const u16* g1s = Wp1 + it * 2048 + w * 512 + l * 8;
        const u16* g2s = Wp2 + it * 2048 + w * 512 + l * 8;
        __builtin_amdgcn_global_load_lds((gbl_t*)g1s, (lds_t*)&WS1[it * 2048 + w * 512], 16, 0, 0);
        __builtin_amdgcn_global_load_lds((gbl_t*)g2s, (lds_t*)&WS2[it * 2048 + w * 512], 16, 0, 0);
    }

    float bb[8];
    #pragma unroll
    for (int t = 0; t < 8; ++t) bb[t] = bias[t * 16 + c];

    float4 xlo[4], xhi[4];
    float gamv[4], betv[4];
    auto prefetch = [&](int tt) {
        int n8 = tt * 32 + w * 8;
        int nb_ = (n8 < N) ? n8 : 0;
        const float* xb = X + ((size_t)(c >> 3) * N + nb_ + (c & 7)) * CC + g * 8;
        #pragma unroll
        for (int s = 0; s < 4; ++s) {
            xlo[s] = *(const float4*)(xb + s * 32);
            xhi[s] = *(const float4*)(xb + s * 32 + 4);
        }
        #pragma unroll
        for (int r = 0; r < 4; ++r) {
            int p = (4 * g + r) & 7;
            gamv[r] = gamma[nb_ + p];
            betv[r] = beta[nb_ + p];
        }
    };
    prefetch(blockIdx.x);

    __syncthreads();   // W1+W2 staged; the ONLY barrier

    for (int t = blockIdx.x; t < ntiles; t += NB) {
        const int n8 = t * 32 + w * 8;
        const bool valid = n8 < N;

        bf16x8 af[4];
        #pragma unroll
        for (int s = 0; s < 4; ++s) {
            unsigned aw[4];
            aw[0] = cvt_pk(xlo[s].x, xlo[s].y); aw[1] = cvt_pk(xlo[s].z, xlo[s].w);
            aw[2] = cvt_pk(xhi[s].x, xhi[s].y); aw[3] = cvt_pk(xhi[s].z, xhi[s].w);
            af[s] = *(bf16x8*)aw;
        }
        float gam[4], bet[4];
        #pragma unroll
        for (int r = 0; r < 4; ++r) { gam[r] = gamv[r]; bet[r] = betv[r]; }

        if (t + NB < ntiles) prefetch(t + NB);

        f32x4 acc[8];
        #pragma unroll
        for (int q = 0; q < 8; ++q) acc[q] = (f32x4){0.f, 0.f, 0.f, 0.f};
        #pragma unroll
        for (int s = 0; s < 4; ++s) {
            bf16x8 bf[8];
            #pragma unroll
            for (int q = 0; q < 8; ++q)
                bf[q] = *(const bf16x8*)&WS1[((q * 4 + s) * 64 + l) * 8];
            #pragma unroll
            for (int q = 0; q < 8; ++q)
                acc[q] = __builtin_amdgcn_mfma_f32_16x16x32_bf16(af[s], bf[q], acc[q], 0, 0, 0);
        }

        float rs[4] = {0.f, 0.f, 0.f, 0.f}, rq[4] = {0.f, 0.f, 0.f, 0.f};
        #pragma unroll
        for (int q = 0; q < 8; ++q)
            #pragma unroll
            for (int r = 0; r < 4; ++r) {
                float h = acc[q][r] + bb[q];
                acc[q][r] = h;
                rs[r] += h;
                rq[r] += h * h;
            }
        #pragma unroll
        for (int d = 1; d < 16; d <<= 1) {
            #pragma unroll
            for (int r = 0; r < 4; ++r) {
                rs[r] += __shfl_xor(rs[r], d);
                rq[r] += __shfl_xor(rq[r], d);
            }
        }
        #pragma unroll
        for (int r = 0; r < 4; ++r) {
            rs[r] += __shfl_xor(rs[r], 32);
            rq[r] += __shfl_xor(rq[r], 32);
        }

        #pragma unroll
        for (int r = 0; r < 4; ++r) {
            float mean = rs[r] * (1.f / 256.f);
            float var  = rq[r] * (1.f / 256.f) - mean * mean;
            float sc = gam[r] * rsqrtf(fmaxf(var, 0.f) + 1e-5f);
            float sh = bet[r] - mean * sc;
            #pragma unroll
            for (int q = 0; q < 8; ++q)
                acc[q][r] = gelu_f(acc[q][r] * sc + sh);
        }

        #pragma unroll
        for (int r = 0; r < 4; ++r) {
            int row = 4 * g + r;
            unsigned tw[4];
            #pragma unroll
            for (int tt = 0; tt < 4; ++tt)
                tw[tt] = cvt_pk(acc[2 * tt][r], acc[2 * tt + 1][r]);
            int colw = (c * 4) ^ ((row & 7) << 2);
            *(uint4*)&TT[w][row][colw] = *(uint4*)tw;
        }
        bf16x8 af2[4];
        #pragma unroll
        for (int s = 0; s < 4; ++s) {
            int colr = (s * 16 + g * 4) ^ ((c & 7) << 2);
            af2[s] = *(const bf16x8*)&TT[w][c][colr];
        }

        f32x4 acc2[8];
        #pragma unroll
        for (int q = 0; q < 8; ++q) acc2[q] = (f32x4){0.f, 0.f, 0.f, 0.f};
        #pragma unroll
        for (int s = 0; s < 4; ++s) {
            bf16x8 bf[8];
            #pragma unroll
            for (int q = 0; q < 8; ++q)
                bf[q] = *(const bf16x8*)&WS2[((q * 4 + s) * 64 + l) * 8];
            #pragma unroll
            for (int q = 0; q < 8; ++q)
                acc2[q] = __builtin_amdgcn_mfma_f32_16x16x32_bf16(af2[s], bf[q], acc2[q], 0, 0, 0);
        }

        if (valid) {
            #pragma unroll
            for (int r = 0; r < 4; ++r) {
                int rr = 4 * g + r;
                int db = rr >> 3, dn = n8 + (rr & 7);
                unsigned zw[4];
                #pragma unroll
                for (int tt = 0; tt < 4; ++tt)
                    zw[tt] = cvt_pk(acc2[2 * tt][r], acc2[2 * tt + 1][r]);
                *(uint4*)(Z + ((size_t)dn * 2 + db) * CC + c * 8) = *(uint4*)zw;
            }
        }
    }
}

// ---------------- K2: aggregate(Z) + b2 + BN2 + GELU2 -> a2 (standard order) ----------------
// TWO nodes per wave (one per 32-lane half); edge loop 4-deep unrolled per half.
__global__ __launch_bounds__(256) void k_agg_bn(
    const u16* __restrict__ Zin, const int* __restrict__ off, const int2* __restrict__ eg,
    const float* __restrict__ b2, const float* __restrict__ g2, const float* __restrict__ be2,
    u16* __restrict__ A2, int N)
{
    __shared__ u16 TW[4][2][256];
    const int wv = threadIdx.x >> 6;
    const int l = threadIdx.x & 63;
    const int half = l >> 5;
    const int h = l & 31;
    const int b = h >> 4;
    const int c = h & 15;
    const int n = blockIdx.x * 8 + wv * 2 + half;
    const bool nv = n < N;
    const int nn = nv ? n : 0;
    const u16* Ab = Zin + b * CC + c * 8;

    float bb[8];
    #pragma unroll
    for (int t = 0; t < 8; ++t) bb[t] = b2[t * 16 + c];

    int s = off[nn];
    int e = nv ? off[nn + 1] : 0;
    float a[8] = {0.f, 0.f, 0.f, 0.f, 0.f, 0.f, 0.f, 0.f};
    for (int j = s; j < e; j += 4) {
        int2 e0 = eg[j], e1 = eg[j + 1], e2 = eg[j + 2], e3 = eg[j + 3];
        int s0 = e0.x;                  float w0 = __int_as_float(e0.y);
        int s1 = (j + 1 < e) ? e1.x : 0; float w1 = (j + 1 < e) ? __int_as_float(e1.y) : 0.f;
        int s2 = (j + 2 < e) ? e2.x : 0; float w2 = (j + 2 < e) ? __int_as_float(e2.y) : 0.f;
        int s3 = (j + 3 < e) ? e3.x : 0; float w3 = (j + 3 < e) ? __int_as_float(e3.y) : 0.f;
        bf16x8 v0 = *(const bf16x8*)(Ab + (size_t)s0 * 256);
        bf16x8 v1 = *(const bf16x8*)(Ab + (size_t)s1 * 256);
        bf16x8 v2 = *(const bf16x8*)(Ab + (size_t)s2 * 256);
        bf16x8 v3 = *(const bf16x8*)(Ab + (size_t)s3 * 256);
        #pragma unroll
        for (int q = 0; q < 8; ++q) {
            a[q] = fmaf(w0, bf2f((u16)v0[q]), a[q]);
            a[q] = fmaf(w1, bf2f((u16)v1[q]), a[q]);
            a[q] = fmaf(w2, bf2f((u16)v2[q]), a[q]);
            a[q] = fmaf(w3, bf2f((u16)v3[q]), a[q]);
        }
    }

    float ss = 0.f, qq = 0.f;
    #pragma unroll
    for (int t = 0; t < 8; ++t) {
        float hh = a[t] + bb[t];
        a[t] = hh;
        ss += hh;
        qq += hh * hh;
    }
    #pragma unroll
    for (int d = 1; d < 32; d <<= 1) {   // stays within the 32-lane half
        ss += __shfl_xor(ss, d);
        qq += __shfl_xor(qq, d);
    }
    float mean = ss * (1.f / 256.f);
    float var  = qq * (1.f / 256.f) - mean * mean;
    float sc = g2[nn] * rsqrtf(fmaxf(var, 0.f) + 1e-5f);
    float sh = be2[nn] - mean * sc;

    #pragma unroll
    for (int t = 0; t < 8; ++t)
        TW[wv][half][b * CC + t * 16 + c] = f2bf(gelu_f(a[t] * sc + sh));
    if (nv) {
        bf16x8 v = *(const bf16x8*)&TW[wv][half][h * 8];
        *(bf16x8*)(A2 + (size_t)nn * 256 + h * 8) = v;
    }
}

// ---------------- K3: aggregate(a2) -> standard-layout f32 output ----------------
__global__ __launch_bounds__(256) void k_agg_out(
    const u16* __restrict__ A2, const int* __restrict__ off, const int2* __restrict__ eg,
    float* __restrict__ Out, int N)
{
    const int wv = threadIdx.x >> 6;
    const int l = threadIdx.x & 63;
    const int half = l >> 5;
    const int h = l & 31;
    const int b = h >> 4;
    const int c = h & 15;
    const int n = blockIdx.x * 8 + wv * 2 + half;
    const bool nv = n < N;
    const int nn = nv ? n : 0;
    const u16* Ab = A2 + h * 8;

    int s = off[nn];
    int e = nv ? off[nn + 1] : 0;
    float a[8] = {0.f, 0.f, 0.f, 0.f, 0.f, 0.f, 0.f, 0.f};
    for (int j = s; j < e; j += 4) {
        int2 e0 = eg[j], e1 = eg[j + 1], e2 = eg[j + 2], e3 = eg[j + 3];
        int s0 = e0.x;                  float w0 = __int_as_float(e0.y);
        int s1 = (j + 1 < e) ? e1.x : 0; float w1 = (j + 1 < e) ? __int_as_float(e1.y) : 0.f;
        int s2 = (j + 2 < e) ? e2.x : 0; float w2 = (j + 2 < e) ? __int_as_float(e2.y) : 0.f;
        int s3 = (j + 3 < e) ? e3.x : 0; float w3 = (j + 3 < e) ? __int_as_float(e3.y) : 0.f;
        bf16x8 v0 = *(const bf16x8*)(Ab + (size_t)s0 * 256);
        bf16x8 v1 = *(const bf16x8*)(Ab + (size_t)s1 * 256);
        bf16x8 v2 = *(const bf16x8*)(Ab + (size_t)s2 * 256);
        bf16x8 v3 = *(const bf16x8*)(Ab + (size_t)s3 * 256);
        #pragma unroll
        for (int q = 0; q < 8; ++q) {
            a[q] = fmaf(w0, bf2f((u16)v0[q]), a[q]);
            a[q] = fmaf(w1, bf2f((u16)v1[q]), a[q]);
            a[q] = fmaf(w2, bf2f((u16)v2[q]), a[q]);
            a[q] = fmaf(w3, bf2f((u16)v3[q]), a[q]);
        }
    }
    if (nv) {
        float* d = Out + ((size_t)b * N + nn) * CC + c * 8;
        *(float4*)&d[0] = make_float4(a[0], a[1], a[2], a[3]);
        *(float4*)&d[4] = make_float4(a[4], a[5], a[6], a[7]);
    }
}

// ---------------- launch ----------------

extern "C" void kernel_launch(void* const* d_in, const int* in_sizes, int n_in,
                              void* d_out, int out_size, void* d_ws, size_t ws_size,
                              hipStream_t stream)
{
    const float* x   = (const float*)d_in[0];
    const int*   ei  = (const int*)d_in[1];
    const float* nrm = (const float*)d_in[2];
    const float* W1  = (const float*)d_in[3];
    const float* b1  = (const float*)d_in[4];
    const float* g1  = (const float*)d_in[5];
    const float* be1 = (const float*)d_in[6];
    const float* W2  = (const float*)d_in[7];
    const float* b2  = (const float*)d_in[8];
    const float* g2  = (const float*)d_in[9];
    const float* be2 = (const float*)d_in[10];

    const int N = in_sizes[5];   // g1 has N elements
    const int E = in_sizes[2];   // norm has E elements
    const int* row = ei;         // edge_index[0] = scatter dst
    const int* col = ei + E;     // edge_index[1] = gather src
    const int nb = (N + 1023) / 1024;

    auto al = [](size_t v) { return (v + 255) & ~(size_t)255; };
    char* p = (char*)d_ws;
    int* off    = (int*)p;   p += al((size_t)(N + 1) * 4);
    int* cur    = (int*)p;   p += al((size_t)N * 4);
    int2* eg    = (int2*)p;  p += al((size_t)(E + 8) * 8);   // +8 pad: tail-slot overreads
    int* bsum   = (int*)p;   p += al((size_t)nb * 4);
    u16* Wp1    = (u16*)p;   p += al((size_t)CC * CC * 2);
    u16* Wp2    = (u16*)p;   p += al((size_t)CC * CC * 2);
    u16* Zbuf   = (u16*)p;   p += al((size_t)2 * N * CC * 2);
    u16* A2buf  = (u16*)p;   p += al((size_t)2 * N * CC * 2);

    // prep (zero cur + both W repacks) then CSR by destination (scan_b folded into scan_c)
    const int prep_n = N + 2 * CC * CC;
    k_prep<<<(prep_n + 255) / 256, 256, 0, stream>>>(cur, N, W1, Wp1, W2, Wp2);
    k_hist<<<(E + 255) / 256, 256, 0, stream>>>(row, cur, E);
    k_scan_a<<<nb, 256, 0, stream>>>(cur, bsum, N);
    k_scan_c<<<nb, 256, 0, stream>>>(cur, bsum, off, N);   // also zeroes cur, writes off[N]
    k_fill<<<(E + 255) / 256, 256, 0, stream>>>(row, col, nrm, off, cur, eg, E);

    const int ga = (N + 7) / 8;
    // K1: persistent fused GEMM1+BN1+GELU1+GEMM2 -> Z
    k_fused_l1<<<512, 256, 0, stream>>>(x, Wp1, Wp2, b1, g1, be1, Zbuf, N);
    // K2: aggregate + b2 + BN2 + GELU2 -> a2 (node-major, standard channel order)
    k_agg_bn<<<ga, 256, 0, stream>>>(Zbuf, off, eg, b2, g2, be2, A2buf, N);
    // K3: aggregate -> standard f32 out (coalesced)
    k_agg_out<<<ga, 256, 0, stream>>>(A2buf, off, eg, (float*)d_out, N);
}